// Round 10
// baseline (261.164 us; speedup 1.0000x reference)
//
#include <hip/hip_runtime.h>
#include <hip/hip_fp16.h>
#include <stdint.h>

// Problem constants (B,C_IN,L fixed by the reference)
#define BB    4
#define CIN   512
#define CRED  256
#define LL    16384
#define NBLK  256      // L / 64
#define WELEM 131072   // elements per weight matrix (256*512)

typedef _Float16 half8 __attribute__((ext_vector_type(8)));
typedef float    f32x4 __attribute__((ext_vector_type(4)));

#define SWZ(r) (((r)&7)<<4)

// ---------------- workspace layout (elements of _Float16) -----------------
// [0, 524288)   : fp16 weights Wq,Wk,Wv,Wo (4 x 131072)
// XB            : XT region, 1024 tiles x 32768 el, FRAGMENT-MAJOR per tile:
//                 el = t*32768 + ks*2048 + l4*512 + j*8  (ks=ch/32, l4=(ch%32)/8,
//                 j=pos-in-tile, 8 contiguous ch).  After qkv_gemm2 consumes
//                 tile t, V_t ([ch 256][pos 64], 16384 el) OVERLAYS its start.
// QB2 / KB2     : Q,K [b][pos 16384][ch 256]
#define XB      524288
#define TILE_EL 32768
#define XTV_EL  (1024 * TILE_EL)          // 33,554,432
#define QB2     (XB + XTV_EL)
#define KB2     (QB2 + 16777216)
#define WS_NEED ((size_t)(KB2 + 16777216) * 2)   // ~135.3 MB

__global__ void convert_weights(const float* __restrict__ Wq,
                                const float* __restrict__ Wk,
                                const float* __restrict__ Wv,
                                const float* __restrict__ Wo,
                                _Float16* __restrict__ dst) {
    int i = blockIdx.x * blockDim.x + threadIdx.x;
    int m = i >> 17;
    int e = i & (WELEM - 1);
    const float* src = (m == 0) ? Wq : (m == 1) ? Wk : (m == 2) ? Wv : Wo;
    dst[(size_t)m * WELEM + e] = (_Float16)src[e];
}

// ================== K1: x1 f32 -> XT fp16 (fragment-major) =================
// 4096 blocks: (tile, 128-ch chunk). 16 KB LDS -> ~8 blocks/CU, streaming.
__global__ __launch_bounds__(256, 4)
void x_transpose(const float* __restrict__ x1, _Float16* __restrict__ ws) {
    __shared__ char lds[16384];            // [64 pos][128 ch] fp16, rows 256 B
    const int tid = threadIdx.x;
    const int blk = blockIdx.x;
    const int t   = blk >> 2;              // tile 0..1023
    const int cc  = blk & 3;               // 128-ch chunk
    const int b   = t >> 8, n = t & 255;
    const int jx  = tid & 15;              // pos quad
    const int rg  = tid >> 4;              // ch octet 0..15

    const float* xp = x1 + ((size_t)b * CIN + cc * 128 + 8 * rg) * LL + n * 64 + 4 * jx;
    f32x4 r[8];
    #pragma unroll
    for (int k = 0; k < 8; ++k)
        r[k] = *(const f32x4*)(xp + (size_t)k * LL);
    asm volatile("" ::: "memory");         // burst all 8 loads before converts
    #pragma unroll
    for (int u = 0; u < 4; ++u) {
        const int j = 4 * jx + u;
        union { _Float16 h[8]; half8 v; } pk;
        #pragma unroll
        for (int k = 0; k < 8; ++k) pk.h[k] = (_Float16)r[k][u];
        *(half8*)(lds + j * 256 + ((16 * rg) ^ SWZ(j))) = pk.v;
    }
    __syncthreads();
    // dump fragment-major: round rr -> ks-in-chunk; contiguous global writes
    _Float16* dst = ws + XB + (size_t)t * TILE_EL + cc * 8192;
    const int l4d = tid >> 6, jd = tid & 63;
    #pragma unroll
    for (int rr = 0; rr < 4; ++rr) {
        half8 v = *(const half8*)(lds + jd * 256 + ((rr * 64 + l4d * 16) ^ SWZ(jd)));
        *(half8*)(dst + rr * 2048 + tid * 8) = v;
    }
}

// ================== K2: Q,K,V = W @ X  — zero-LDS streaming ================
// 1024 blocks x 512 thr (8 waves x 32 ch). B-frags direct from global XT
// (fragment-major => 4x128B lines per load instr). One barrier (before the
// V overlay store). ~110 regs/wave -> 4 waves/SIMD (16 waves/CU).
__global__ __launch_bounds__(512, 4)
void qkv_gemm2(const _Float16* __restrict__ W,
               const float* __restrict__ bq, const float* __restrict__ bk,
               const float* __restrict__ bv, _Float16* ws) {
    const int tid = threadIdx.x;
    const int wid = tid >> 6;              // 0..7
    const int l15 = tid & 15;
    const int l4  = (tid & 63) >> 4;
    const int t   = blockIdx.x;
    const int b   = t >> 8, n = t & 255;

    const _Float16* xt = ws + XB + (size_t)t * TILE_EL;
    f32x4 accV[2][4];                      // V acc survives the barrier

    #pragma unroll
    for (int p = 0; p < 3; ++p) {
        f32x4 acc[2][4];
        #pragma unroll
        for (int mt = 0; mt < 2; ++mt)
            #pragma unroll
            for (int q = 0; q < 4; ++q) acc[mt][q] = (f32x4){0.f, 0.f, 0.f, 0.f};

        const _Float16* wp = W + (size_t)p * WELEM
                           + (size_t)(wid * 32 + l15) * CIN + l4 * 8;
        half8 wf[2][2], xf[2][4];
        #pragma unroll
        for (int mt = 0; mt < 2; ++mt) wf[0][mt] = *(const half8*)(wp + mt * 16 * CIN);
        #pragma unroll
        for (int nt = 0; nt < 4; ++nt)
            xf[0][nt] = *(const half8*)(xt + l4 * 512 + (nt * 16 + l15) * 8);

        #pragma unroll
        for (int ks = 0; ks < 16; ++ks) {
            const int c = ks & 1, nx = c ^ 1;
            if (ks < 15) {
                #pragma unroll
                for (int mt = 0; mt < 2; ++mt)
                    wf[nx][mt] = *(const half8*)(wp + mt * 16 * CIN + (ks + 1) * 32);
                #pragma unroll
                for (int nt = 0; nt < 4; ++nt)
                    xf[nx][nt] = *(const half8*)(xt + (ks + 1) * 2048 + l4 * 512
                                                 + (nt * 16 + l15) * 8);
            }
            #pragma unroll
            for (int mt = 0; mt < 2; ++mt)
                #pragma unroll
                for (int nt = 0; nt < 4; ++nt)
                    acc[mt][nt] = __builtin_amdgcn_mfma_f32_16x16x32_f16(
                        wf[c][mt], xf[c][nt], acc[mt][nt], 0, 0, 0);
        }

        if (p < 2) {
            _Float16* dst = ws + (p ? KB2 : QB2) + ((size_t)b * LL + n * 64) * CRED;
            const float* bias = p ? bk : bq;
            #pragma unroll
            for (int mt = 0; mt < 2; ++mt) {
                const int c0 = wid * 32 + mt * 16 + l4 * 4;
                f32x4 b4 = *(const f32x4*)(bias + c0);
                #pragma unroll
                for (int nt = 0; nt < 4; ++nt) {
                    const int pos = nt * 16 + l15;
                    union { _Float16 h[4]; uint64_t q; } pk;
                    #pragma unroll
                    for (int ri = 0; ri < 4; ++ri)
                        pk.h[ri] = (_Float16)(acc[mt][nt][ri] + b4[ri]);
                    *(uint64_t*)(dst + (size_t)pos * CRED + c0) = pk.q;
                }
            }
        } else {
            #pragma unroll
            for (int mt = 0; mt < 2; ++mt)
                #pragma unroll
                for (int q = 0; q < 4; ++q) accV[mt][q] = acc[mt][q];
        }
    }

    __syncthreads();   // ALL waves done reading XT_t -> V may overlay it
    {
        _Float16* vdst = ws + XB + (size_t)t * TILE_EL;   // [ch 256][pos 64]
        #pragma unroll
        for (int mt = 0; mt < 2; ++mt) {
            const int c0 = wid * 32 + mt * 16 + l4 * 4;
            f32x4 b4 = *(const f32x4*)(bv + c0);
            #pragma unroll
            for (int nt = 0; nt < 4; ++nt) {
                const int pos = nt * 16 + l15;
                #pragma unroll
                for (int ri = 0; ri < 4; ++ri)
                    vdst[(size_t)(c0 + ri) * 64 + pos] =
                        (_Float16)(accV[mt][nt][ri] + b4[ri]);
            }
        }
    }
}

// ================ K3: attention + output projection ========================
#define BH_OFF 0
#define BP_OFF 32768
#define LDS_B  40960

__global__ __launch_bounds__(256, 3)
void attn_out(const float* __restrict__ mask, const _Float16* __restrict__ ws,
              const float* __restrict__ bo, float* __restrict__ out) {
    extern __shared__ char lds[];
    const int tid = threadIdx.x;
    const int wid = tid >> 6;
    const int l15 = tid & 15;
    const int l4  = (tid & 63) >> 4;
    const int b   = blockIdx.x >> 8;
    const int n   = blockIdx.x & 255;
    const int t   = blockIdx.x;

    const _Float16* qt = ws + QB2 + ((size_t)b * LL + n * 64) * CRED;
    const _Float16* kt = ws + KB2 + ((size_t)b * LL + n * 64) * CRED;
    const _Float16* vt = ws + XB + (size_t)t * TILE_EL;   // [ch 256][pos 64]
    const _Float16* Wo = ws + 3 * (size_t)WELEM;

    // -------- S = (Q^T K)*scale + in-register masked softmax -> P ---------
    {
        const int i0 = wid * 16;
        f32x4 sa[4];
        #pragma unroll
        for (int jt = 0; jt < 4; ++jt) sa[jt] = (f32x4){0.f, 0.f, 0.f, 0.f};
        #pragma unroll
        for (int ks = 0; ks < 8; ++ks) {
            half8 qa = *(const half8*)(qt + (size_t)(i0 + l15) * CRED + ks * 32 + l4 * 8);
            #pragma unroll
            for (int jt = 0; jt < 4; ++jt) {
                half8 kf = *(const half8*)(kt + (size_t)(jt * 16 + l15) * CRED + ks * 32 + l4 * 8);
                sa[jt] = __builtin_amdgcn_mfma_f32_16x16x32_f16(qa, kf, sa[jt], 0, 0, 0);
            }
        }
        float msk[4];
        #pragma unroll
        for (int jt = 0; jt < 4; ++jt)
            msk[jt] = mask[(size_t)b * LL + n * 64 + jt * 16 + l15];
        #pragma unroll
        for (int ri = 0; ri < 4; ++ri) {
            float v[4];
            #pragma unroll
            for (int jt = 0; jt < 4; ++jt)
                v[jt] = (msk[jt] == 0.f) ? -1e30f : sa[jt][ri] * 0.0625f;
            float mx = fmaxf(fmaxf(v[0], v[1]), fmaxf(v[2], v[3]));
            mx = fmaxf(mx, __shfl_xor(mx, 1));
            mx = fmaxf(mx, __shfl_xor(mx, 2));
            mx = fmaxf(mx, __shfl_xor(mx, 4));
            mx = fmaxf(mx, __shfl_xor(mx, 8));
            float e[4], sum = 0.f;
            #pragma unroll
            for (int jt = 0; jt < 4; ++jt) { e[jt] = __expf(v[jt] - mx); sum += e[jt]; }
            sum += __shfl_xor(sum, 1);
            sum += __shfl_xor(sum, 2);
            sum += __shfl_xor(sum, 4);
            sum += __shfl_xor(sum, 8);
            const float inv = 1.f / sum;
            const int i = i0 + l4 * 4 + ri;
            #pragma unroll
            for (int jt = 0; jt < 4; ++jt) {
                const int j = jt * 16 + l15;
                *(_Float16*)(lds + BP_OFF + i * 128 + ((2 * j) ^ SWZ(i))) =
                    (_Float16)(e[jt] * inv);
            }
        }
    }
    __syncthreads();   // P ready

    // -------- H = relu(V @ P^T)  (V frags direct from global) -------------
    {
        const int cb = wid * 64;
        f32x4 pv[4][4];
        #pragma unroll
        for (int m = 0; m < 4; ++m)
            #pragma unroll
            for (int q = 0; q < 4; ++q) pv[m][q] = (f32x4){0.f, 0.f, 0.f, 0.f};
        #pragma unroll
        for (int ks = 0; ks < 2; ++ks) {
            const int kb = ks * 64 + l4 * 16;
            half8 pb[4];
            #pragma unroll
            for (int nt = 0; nt < 4; ++nt) {
                const int i = nt * 16 + l15;
                pb[nt] = *(const half8*)(lds + BP_OFF + i * 128 + (kb ^ SWZ(i)));
            }
            #pragma unroll
            for (int mt = 0; mt < 4; ++mt) {
                half8 va = *(const half8*)(vt + (size_t)(cb + mt * 16 + l15) * 64 + ks * 32 + l4 * 8);
                #pragma unroll
                for (int nt = 0; nt < 4; ++nt)
                    pv[mt][nt] = __builtin_amdgcn_mfma_f32_16x16x32_f16(va, pb[nt], pv[mt][nt], 0, 0, 0);
            }
        }
        #pragma unroll
        for (int mt = 0; mt < 4; ++mt) {
            const int c0 = cb + mt * 16 + l4 * 4;
            #pragma unroll
            for (int nt = 0; nt < 4; ++nt) {
                const int j = nt * 16 + l15;
                union { _Float16 h[4]; uint64_t q; } hp;
                #pragma unroll
                for (int ri = 0; ri < 4; ++ri)
                    hp.h[ri] = (_Float16)fmaxf(pv[mt][nt][ri], 0.f);
                *(uint64_t*)(lds + BH_OFF + j * 512 + ((2 * c0) ^ SWZ(j))) = hp.q;
            }
        }
    }
    __syncthreads();   // H ready

    // -------- Out = Wo @ H + bo  (M=512, K=256, N=64) ---------------------
    #pragma unroll
    for (int op = 0; op < 2; ++op) {
        const int mbo = wid * 128 + op * 64;
        const _Float16* wob = Wo + (size_t)(mbo + l15) * CRED + l4 * 8;
        f32x4 oa[4][4];
        #pragma unroll
        for (int m = 0; m < 4; ++m)
            #pragma unroll
            for (int q = 0; q < 4; ++q) oa[m][q] = (f32x4){0.f, 0.f, 0.f, 0.f};
        #pragma unroll 4
        for (int ks = 0; ks < 8; ++ks) {
            const int kb = ks * 64 + l4 * 16;
            half8 hb[4];
            #pragma unroll
            for (int nt = 0; nt < 4; ++nt) {
                const int i = nt * 16 + l15;
                hb[nt] = *(const half8*)(lds + BH_OFF + i * 512 + (kb ^ SWZ(i)));
            }
            #pragma unroll
            for (int mt = 0; mt < 4; ++mt) {
                half8 wa = *(const half8*)(wob + mt * 16 * CRED + ks * 32);
                #pragma unroll
                for (int nt = 0; nt < 4; ++nt)
                    oa[mt][nt] = __builtin_amdgcn_mfma_f32_16x16x32_f16(wa, hb[nt], oa[mt][nt], 0, 0, 0);
            }
        }
        #pragma unroll
        for (int mt = 0; mt < 4; ++mt) {
            const int o0 = mbo + mt * 16 + l4 * 4;
            f32x4 bov = *(const f32x4*)(bo + o0);
            #pragma unroll
            for (int ri = 0; ri < 4; ++ri) {
                float* orow = out + ((size_t)b * CIN + (o0 + ri)) * LL + n * 64;
                #pragma unroll
                for (int nt = 0; nt < 4; ++nt)
                    orow[nt * 16 + l15] = oa[mt][nt][ri] + bov[ri];
            }
        }
    }
}

// ================= Fallback: R5 fused kernel (verified, 168 us) ============
#define XT_OFF 0
#define Q_OFF  0
#define K_OFF  32768
#define V_OFF  32768
#define H_OFF  0
#define P_OFF  65536
#define MSK_OFF 73728
#define LDS_BYTES 73984

__global__ __launch_bounds__(256, 2)
void att_fused(const float* __restrict__ x1, const float* __restrict__ mask,
               const _Float16* __restrict__ W,
               const float* __restrict__ bq, const float* __restrict__ bk,
               const float* __restrict__ bv, const float* __restrict__ bo,
               float* __restrict__ out) {
    extern __shared__ char lds[];
    const int tid  = threadIdx.x;
    const int wid  = tid >> 6;
    const int lane = tid & 63;
    const int l15  = lane & 15;
    const int l4   = lane >> 4;
    const int blk  = blockIdx.x;
    const int b    = blk >> 8;
    const int n    = blk & 255;

    const _Float16* Wq = W;
    const _Float16* Wk = W + WELEM;
    const _Float16* Wv = W + 2 * WELEM;
    const _Float16* Wo = W + 3 * WELEM;

    {
        const int jx = tid & 15;
        const int rb = tid >> 4;
        const float* xbase = x1 + ((size_t)b * CIN + 2 * rb) * LL + n * 64 + 4 * jx;
        #pragma unroll
        for (int i = 0; i < 16; ++i) {
            f32x4 a = *(const f32x4*)(xbase + (size_t)(32 * i) * LL);
            f32x4 c = *(const f32x4*)(xbase + (size_t)(32 * i + 1) * LL);
            const int col = 4 * rb + 64 * i;
            #pragma unroll
            for (int u = 0; u < 4; ++u) {
                union { _Float16 h[2]; uint32_t w; } p;
                p.h[0] = (_Float16)a[u];
                p.h[1] = (_Float16)c[u];
                const int j = 4 * jx + u;
                *(uint32_t*)(lds + XT_OFF + j * 1024 + (col ^ SWZ(j))) = p.w;
            }
        }
        if (tid < 64)
            *(float*)(lds + MSK_OFF + tid * 4) = mask[(size_t)b * LL + n * 64 + tid];
    }
    __syncthreads();

    uint64_t qh[4][4], kh[4][4], vh[4][4];
    #pragma unroll
    for (int pass = 0; pass < 4; ++pass) {
        f32x4 aQ[4], aK[4], aV[4];
        #pragma unroll
        for (int q = 0; q < 4; ++q) {
            aQ[q] = (f32x4){0.f, 0.f, 0.f, 0.f};
            aK[q] = (f32x4){0.f, 0.f, 0.f, 0.f};
            aV[q] = (f32x4){0.f, 0.f, 0.f, 0.f};
        }
        const int mrow = wid * 64 + pass * 16 + l15;
        const _Float16* wqp = Wq + (size_t)mrow * CIN + l4 * 8;
        const _Float16* wkp = Wk + (size_t)mrow * CIN + l4 * 8;
        const _Float16* wvp = Wv + (size_t)mrow * CIN + l4 * 8;
        #pragma unroll 4
        for (int ks = 0; ks < 16; ++ks) {
            const int kb = ks * 64 + l4 * 16;
            half8 xb[4];
            #pragma unroll
            for (int nt = 0; nt < 4; ++nt) {
                const int j = nt * 16 + l15;
                xb[nt] = *(const half8*)(lds + XT_OFF + j * 1024 + (kb ^ SWZ(j)));
            }
            half8 aq = *(const half8*)(wqp + ks * 32);
            half8 ak = *(const half8*)(wkp + ks * 32);
            half8 av = *(const half8*)(wvp + ks * 32);
            #pragma unroll
            for (int nt = 0; nt < 4; ++nt) {
                aQ[nt] = __builtin_amdgcn_mfma_f32_16x16x32_f16(aq, xb[nt], aQ[nt], 0, 0, 0);
                aK[nt] = __builtin_amdgcn_mfma_f32_16x16x32_f16(ak, xb[nt], aK[nt], 0, 0, 0);
                aV[nt] = __builtin_amdgcn_mfma_f32_16x16x32_f16(av, xb[nt], aV[nt], 0, 0, 0);
            }
        }
        const int c0 = wid * 64 + pass * 16 + l4 * 4;
        f32x4 bqv = *(const f32x4*)(bq + c0);
        f32x4 bkv = *(const f32x4*)(bk + c0);
        f32x4 bvv = *(const f32x4*)(bv + c0);
        #pragma unroll
        for (int nt = 0; nt < 4; ++nt) {
            union { _Float16 h[4]; uint64_t q; } qp, kp, vp;
            #pragma unroll
            for (int ri = 0; ri < 4; ++ri) {
                qp.h[ri] = (_Float16)(aQ[nt][ri] + bqv[ri]);
                kp.h[ri] = (_Float16)(aK[nt][ri] + bkv[ri]);
                vp.h[ri] = (_Float16)(aV[nt][ri] + bvv[ri]);
            }
            qh[pass][nt] = qp.q;
            kh[pass][nt] = kp.q;
            vh[pass][nt] = vp.q;
        }
    }
    __syncthreads();

    #pragma unroll
    for (int pass = 0; pass < 4; ++pass) {
        const int c0 = wid * 64 + pass * 16 + l4 * 4;
        #pragma unroll
        for (int nt = 0; nt < 4; ++nt) {
            const int j = nt * 16 + l15;
            *(uint64_t*)(lds + Q_OFF + j * 512 + ((2 * c0) ^ SWZ(j))) = qh[pass][nt];
            *(uint64_t*)(lds + K_OFF + j * 512 + ((2 * c0) ^ SWZ(j))) = kh[pass][nt];
        }
    }
    __syncthreads();

    {
        const int i0 = wid * 16;
        f32x4 sa[4];
        #pragma unroll
        for (int jt = 0; jt < 4; ++jt) sa[jt] = (f32x4){0.f, 0.f, 0.f, 0.f};
        #pragma unroll
        for (int ks = 0; ks < 8; ++ks) {
            const int kb = ks * 64 + l4 * 16;
            const int iq = i0 + l15;
            half8 qa = *(const half8*)(lds + Q_OFF + iq * 512 + (kb ^ SWZ(iq)));
            #pragma unroll
            for (int jt = 0; jt < 4; ++jt) {
                const int jr = jt * 16 + l15;
                half8 kf = *(const half8*)(lds + K_OFF + jr * 512 + (kb ^ SWZ(jr)));
                sa[jt] = __builtin_amdgcn_mfma_f32_16x16x32_f16(qa, kf, sa[jt], 0, 0, 0);
            }
        }
        float msk[4];
        #pragma unroll
        for (int jt = 0; jt < 4; ++jt)
            msk[jt] = *(const float*)(lds + MSK_OFF + (jt * 16 + l15) * 4);
        #pragma unroll
        for (int ri = 0; ri < 4; ++ri) {
            float v[4];
            #pragma unroll
            for (int jt = 0; jt < 4; ++jt)
                v[jt] = (msk[jt] == 0.f) ? -1e30f : sa[jt][ri] * 0.0625f;
            float mx = fmaxf(fmaxf(v[0], v[1]), fmaxf(v[2], v[3]));
            mx = fmaxf(mx, __shfl_xor(mx, 1));
            mx = fmaxf(mx, __shfl_xor(mx, 2));
            mx = fmaxf(mx, __shfl_xor(mx, 4));
            mx = fmaxf(mx, __shfl_xor(mx, 8));
            float e[4], sum = 0.f;
            #pragma unroll
            for (int jt = 0; jt < 4; ++jt) { e[jt] = __expf(v[jt] - mx); sum += e[jt]; }
            sum += __shfl_xor(sum, 1);
            sum += __shfl_xor(sum, 2);
            sum += __shfl_xor(sum, 4);
            sum += __shfl_xor(sum, 8);
            const float inv = 1.f / sum;
            const int i = i0 + l4 * 4 + ri;
            #pragma unroll
            for (int jt = 0; jt < 4; ++jt) {
                const int j = jt * 16 + l15;
                *(_Float16*)(lds + P_OFF + i * 128 + ((2 * j) ^ SWZ(i))) =
                    (_Float16)(e[jt] * inv);
            }
        }
    }
    __syncthreads();

    #pragma unroll
    for (int pass = 0; pass < 4; ++pass) {
        const int c0 = wid * 64 + pass * 16 + l4 * 4;
        #pragma unroll
        for (int nt = 0; nt < 4; ++nt) {
            const int j = nt * 16 + l15;
            const uint64_t v64 = vh[pass][nt];
            #pragma unroll
            for (int ri = 0; ri < 4; ++ri) {
                const int c = c0 + ri;
                *(uint16_t*)(lds + V_OFF + c * 128 + ((2 * j) ^ SWZ(c))) =
                    (uint16_t)(v64 >> (16 * ri));
            }
        }
    }
    __syncthreads();

    {
        const int cb = wid * 64;
        f32x4 pv[4][4];
        #pragma unroll
        for (int m = 0; m < 4; ++m)
            #pragma unroll
            for (int q = 0; q < 4; ++q) pv[m][q] = (f32x4){0.f, 0.f, 0.f, 0.f};
        #pragma unroll
        for (int ks = 0; ks < 2; ++ks) {
            const int kb = ks * 64 + l4 * 16;
            half8 pb[4];
            #pragma unroll
            for (int nt = 0; nt < 4; ++nt) {
                const int i = nt * 16 + l15;
                pb[nt] = *(const half8*)(lds + P_OFF + i * 128 + (kb ^ SWZ(i)));
            }
            #pragma unroll
            for (int mt = 0; mt < 4; ++mt) {
                const int c = cb + mt * 16 + l15;
                half8 va = *(const half8*)(lds + V_OFF + c * 128 + (kb ^ SWZ(c)));
                #pragma unroll
                for (int nt = 0; nt < 4; ++nt)
                    pv[mt][nt] = __builtin_amdgcn_mfma_f32_16x16x32_f16(va, pb[nt], pv[mt][nt], 0, 0, 0);
            }
        }
        #pragma unroll
        for (int mt = 0; mt < 4; ++mt) {
            const int c0 = cb + mt * 16 + l4 * 4;
            #pragma unroll
            for (int nt = 0; nt < 4; ++nt) {
                const int j = nt * 16 + l15;
                union { _Float16 h[4]; uint64_t q; } hp;
                #pragma unroll
                for (int ri = 0; ri < 4; ++ri)
                    hp.h[ri] = (_Float16)fmaxf(pv[mt][nt][ri], 0.f);
                *(uint64_t*)(lds + H_OFF + j * 512 + ((2 * c0) ^ SWZ(j))) = hp.q;
            }
        }
    }
    __syncthreads();

    #pragma unroll
    for (int op = 0; op < 2; ++op) {
        const int mbo = wid * 128 + op * 64;
        const _Float16* wob = Wo + (size_t)(mbo + l15) * CRED + l4 * 8;
        f32x4 oa[4][4];
        #pragma unroll
        for (int m = 0; m < 4; ++m)
            #pragma unroll
            for (int q = 0; q < 4; ++q) oa[m][q] = (f32x4){0.f, 0.f, 0.f, 0.f};
        #pragma unroll 4
        for (int ks = 0; ks < 8; ++ks) {
            const int kb = ks * 64 + l4 * 16;
            half8 hb[4];
            #pragma unroll
            for (int nt = 0; nt < 4; ++nt) {
                const int i = nt * 16 + l15;
                hb[nt] = *(const half8*)(lds + H_OFF + i * 512 + (kb ^ SWZ(i)));
            }
            #pragma unroll
            for (int mt = 0; mt < 4; ++mt) {
                half8 wa = *(const half8*)(wob + mt * 16 * CRED + ks * 32);
                #pragma unroll
                for (int nt = 0; nt < 4; ++nt)
                    oa[mt][nt] = __builtin_amdgcn_mfma_f32_16x16x32_f16(wa, hb[nt], oa[mt][nt], 0, 0, 0);
            }
        }
        #pragma unroll
        for (int mt = 0; mt < 4; ++mt) {
            const int o0 = mbo + mt * 16 + l4 * 4;
            f32x4 bov = *(const f32x4*)(bo + o0);
            #pragma unroll
            for (int ri = 0; ri < 4; ++ri) {
                float* orow = out + ((size_t)b * CIN + (o0 + ri)) * LL + n * 64;
                #pragma unroll
                for (int nt = 0; nt < 4; ++nt)
                    orow[nt * 16 + l15] = oa[mt][nt][ri] + bov[ri];
            }
        }
    }
}

extern "C" void kernel_launch(void* const* d_in, const int* in_sizes, int n_in,
                              void* d_out, int out_size, void* d_ws, size_t ws_size,
                              hipStream_t stream) {
    const float* x1   = (const float*)d_in[0];
    // d_in[1] = x2 : unused by the reference
    const float* mask = (const float*)d_in[2];
    const float* Wq   = (const float*)d_in[3];
    const float* bq   = (const float*)d_in[4];
    const float* Wk   = (const float*)d_in[5];
    const float* bk   = (const float*)d_in[6];
    const float* Wv   = (const float*)d_in[7];
    const float* bv   = (const float*)d_in[8];
    const float* Wo   = (const float*)d_in[9];
    const float* bo   = (const float*)d_in[10];
    float* out = (float*)d_out;
    _Float16* wbuf = (_Float16*)d_ws;

    convert_weights<<<2048, 256, 0, stream>>>(Wq, Wk, Wv, Wo, wbuf);

    if (ws_size >= WS_NEED) {
        x_transpose<<<4096, 256, 0, stream>>>(x1, wbuf);
        qkv_gemm2<<<BB * NBLK, 512, 0, stream>>>(wbuf, bq, bk, bv, wbuf);
        attn_out<<<BB * NBLK, 256, LDS_B, stream>>>(mask, wbuf, bo, out);
    } else {
        (void)hipFuncSetAttribute((const void*)att_fused,
                                  hipFuncAttributeMaxDynamicSharedMemorySize, LDS_BYTES);
        att_fused<<<BB * NBLK, 256, LDS_BYTES, stream>>>(x1, mask, wbuf, bq, bk, bv, bo, out);
    }
}

// Round 11
// 182.960 us; speedup vs baseline: 1.4274x; 1.4274x over previous
//
#include <hip/hip_runtime.h>
#include <hip/hip_fp16.h>
#include <stdint.h>

// Problem constants (B,C_IN,L fixed by the reference)
#define BB    4
#define CIN   512
#define CRED  256
#define LL    16384
#define NBLK  256      // L / 64
#define WELEM 131072   // elements per weight matrix

typedef _Float16 half8 __attribute__((ext_vector_type(8)));
typedef float    f32x4 __attribute__((ext_vector_type(4)));

#define SWZ(r) (((r)&7)<<4)

// ---------------- workspace layout (elements of _Float16) -----------------
// [0, 524288)  : weights, FRAGMENT-MAJOR (main path)
//   p<3 (K=512): addr = p*WELEM + m16*8192 + ks*512 + l4*128 + l15*8 + e
//   p=3 (K=256): addr = 3*WELEM + m16*4096 + ks*512 + l4*128 + l15*8 + e
// QB: Q tiles, 1024 x 16384 el, per-tile [64 pos][256 ch]
// KB: K tiles, same layout
// VB: V tiles, per-tile [256 ch][64 pos]
#define QB      524288
#define KB      (QB + 16777216)
#define VB      (KB + 16777216)
#define WS_NEED ((size_t)(VB + 16777216) * 2)   // ~101.7 MB (proven available)

// ---- fragment-major weight conversion (main path) ----
__global__ void convert_weights_fm(const float* __restrict__ Wq,
                                   const float* __restrict__ Wk,
                                   const float* __restrict__ Wv,
                                   const float* __restrict__ Wo,
                                   _Float16* __restrict__ dst) {
    int i = blockIdx.x * blockDim.x + threadIdx.x;   // 0 .. 4*131072-1
    int p = i >> 17;
    int e17 = i & (WELEM - 1);
    const float* src = (p == 0) ? Wq : (p == 1) ? Wk : (p == 2) ? Wv : Wo;
    const int Kd = (p < 3) ? 512 : 256;
    const int sh = (p < 3) ? 13 : 12;
    const int m16 = e17 >> sh;
    const int rem = e17 & ((1 << sh) - 1);
    const int ks  = rem >> 9;
    const int l4  = (rem >> 7) & 3;
    const int l15 = (rem >> 3) & 15;
    const int ee  = rem & 7;
    const int r = m16 * 16 + l15;
    const int k = ks * 32 + l4 * 8 + ee;
    dst[(size_t)p * WELEM + e17] = (_Float16)src[(size_t)r * Kd + k];
}

// ---- row-major conversion (fallback path only) ----
__global__ void convert_weights_rm(const float* __restrict__ Wq,
                                   const float* __restrict__ Wk,
                                   const float* __restrict__ Wv,
                                   const float* __restrict__ Wo,
                                   _Float16* __restrict__ dst) {
    int i = blockIdx.x * blockDim.x + threadIdx.x;
    int m = i >> 17;
    int e = i & (WELEM - 1);
    const float* src = (m == 0) ? Wq : (m == 1) ? Wk : (m == 2) ? Wv : Wo;
    dst[(size_t)m * WELEM + e] = (_Float16)src[e];
}

// =================== K2: Q,K,V = W @ X  (single kernel) ====================
// 1024 blocks (one per 64-pos tile), 256 thr / 4 waves, LB(256,2) -> 256
// regs/wave, LDS 64 KB (XT) -> 2 blocks/CU.  Q+K in ONE interleaved k-loop
// (32 MFMA / 12 loads per ks -> 2 waves/SIMD cover L2 latency); V pass
// reuses resident XT; V repacked through dead XT region for coalesced dump.
__global__ __launch_bounds__(256, 2)
void qkv_fused(const float* __restrict__ x1, const _Float16* __restrict__ W,
               const float* __restrict__ bq, const float* __restrict__ bk,
               const float* __restrict__ bv, _Float16* __restrict__ ws) {
    extern __shared__ char lds[];          // XT [64 pos][512 ch] fp16, rows 1024 B
    const int tid = threadIdx.x;
    const int wid = tid >> 6;
    const int l15 = tid & 15;
    const int l4  = (tid & 63) >> 4;
    const int t   = blockIdx.x;
    const int b   = t >> 8, n = t & 255;

    // -------- burst staging (R9-verified): 32 loads in flight, then commit
    {
        const int jx = tid & 15;           // position quad
        const int rg = tid >> 4;           // channel-octet group 0..15
        const float* xp = x1 + ((size_t)b * CIN + 8 * rg) * LL + n * 64 + 4 * jx;
        f32x4 st[4][8];
        #pragma unroll
        for (int i = 0; i < 4; ++i)
            #pragma unroll
            for (int r8 = 0; r8 < 8; ++r8)
                st[i][r8] = *(const f32x4*)(xp + (size_t)(128 * i + r8) * LL);
        asm volatile("" ::: "memory");
        #pragma unroll
        for (int i = 0; i < 4; ++i) {
            #pragma unroll
            for (int u = 0; u < 4; ++u) {
                const int j = 4 * jx + u;
                union { _Float16 h[8]; half8 v; } pk;
                #pragma unroll
                for (int r8 = 0; r8 < 8; ++r8) pk.h[r8] = (_Float16)st[i][r8][u];
                *(half8*)(lds + j * 1024 + ((16 * rg + 256 * i) ^ SWZ(j))) = pk.v;
            }
        }
    }
    __syncthreads();

    const int fbase = l4 * 128 + l15 * 8;  // lane offset within a weight frag slot

    // -------- pass A: Q and K interleaved (acc 128 regs, fits 256 budget) --
    f32x4 aQ[4][4], aK[4][4];
    #pragma unroll
    for (int mt = 0; mt < 4; ++mt)
        #pragma unroll
        for (int q = 0; q < 4; ++q) {
            aQ[mt][q] = (f32x4){0.f, 0.f, 0.f, 0.f};
            aK[mt][q] = (f32x4){0.f, 0.f, 0.f, 0.f};
        }
    {
        const _Float16* wqf = W + (size_t)(wid * 4) * 8192 + fbase;
        const _Float16* wkf = wqf + WELEM;
        #pragma unroll
        for (int i = 0; i < 16; ++i) {
            const int ks = (i + wid * 4) & 15;       // wave-staggered k order
            half8 xf[4];
            #pragma unroll
            for (int nt = 0; nt < 4; ++nt) {
                const int j = nt * 16 + l15;
                xf[nt] = *(const half8*)(lds + j * 1024 + ((ks * 64 + l4 * 16) ^ SWZ(j)));
            }
            #pragma unroll
            for (int mt = 0; mt < 4; ++mt) {
                half8 qf = *(const half8*)(wqf + mt * 8192 + ks * 512);
                half8 kf = *(const half8*)(wkf + mt * 8192 + ks * 512);
                #pragma unroll
                for (int nt = 0; nt < 4; ++nt) {
                    aQ[mt][nt] = __builtin_amdgcn_mfma_f32_16x16x32_f16(qf, xf[nt], aQ[mt][nt], 0, 0, 0);
                    aK[mt][nt] = __builtin_amdgcn_mfma_f32_16x16x32_f16(kf, xf[nt], aK[mt][nt], 0, 0, 0);
                }
            }
        }
    }
    // stores: per-tile compact [pos][ch], u64 (32B runs); fire-and-forget
    {
        _Float16* qdst = ws + QB + (size_t)t * 16384;
        _Float16* kdst = ws + KB + (size_t)t * 16384;
        #pragma unroll
        for (int mt = 0; mt < 4; ++mt) {
            const int c0 = wid * 64 + mt * 16 + l4 * 4;
            f32x4 bq4 = *(const f32x4*)(bq + c0);
            f32x4 bk4 = *(const f32x4*)(bk + c0);
            #pragma unroll
            for (int nt = 0; nt < 4; ++nt) {
                const int pos = nt * 16 + l15;
                union { _Float16 h[4]; uint64_t q; } qp, kp;
                #pragma unroll
                for (int ri = 0; ri < 4; ++ri) {
                    qp.h[ri] = (_Float16)(aQ[mt][nt][ri] + bq4[ri]);
                    kp.h[ri] = (_Float16)(aK[mt][nt][ri] + bk4[ri]);
                }
                *(uint64_t*)(qdst + (size_t)pos * 256 + c0) = qp.q;
                *(uint64_t*)(kdst + (size_t)pos * 256 + c0) = kp.q;
            }
        }
    }

    // -------- pass B: V (XT still resident; no re-stage) -------------------
    f32x4 aV[4][4];
    #pragma unroll
    for (int mt = 0; mt < 4; ++mt)
        #pragma unroll
        for (int q = 0; q < 4; ++q) aV[mt][q] = (f32x4){0.f, 0.f, 0.f, 0.f};
    {
        const _Float16* wvf = W + 2 * (size_t)WELEM + (size_t)(wid * 4) * 8192 + fbase;
        #pragma unroll
        for (int i = 0; i < 16; ++i) {
            const int ks = (i + wid * 4) & 15;
            half8 xf[4];
            #pragma unroll
            for (int nt = 0; nt < 4; ++nt) {
                const int j = nt * 16 + l15;
                xf[nt] = *(const half8*)(lds + j * 1024 + ((ks * 64 + l4 * 16) ^ SWZ(j)));
            }
            #pragma unroll
            for (int mt = 0; mt < 4; ++mt) {
                half8 vf = *(const half8*)(wvf + mt * 8192 + ks * 512);
                #pragma unroll
                for (int nt = 0; nt < 4; ++nt)
                    aV[mt][nt] = __builtin_amdgcn_mfma_f32_16x16x32_f16(vf, xf[nt], aV[mt][nt], 0, 0, 0);
            }
        }
    }
    __syncthreads();   // all XT reads done -> XT region dead, reuse for V repack

    // V repack: LDS [256 ch][64 pos] (u16 scatter, cheap), then coalesced dump
    {
        _Float16* vl = (_Float16*)lds;
        #pragma unroll
        for (int mt = 0; mt < 4; ++mt) {
            const int c0 = wid * 64 + mt * 16 + l4 * 4;
            f32x4 bv4 = *(const f32x4*)(bv + c0);
            #pragma unroll
            for (int nt = 0; nt < 4; ++nt) {
                const int pos = nt * 16 + l15;
                #pragma unroll
                for (int ri = 0; ri < 4; ++ri)
                    vl[(size_t)(c0 + ri) * 64 + pos] = (_Float16)(aV[mt][nt][ri] + bv4[ri]);
            }
        }
    }
    __syncthreads();
    {
        _Float16* vdst = ws + VB + (size_t)t * 16384;
        const _Float16* vl = (const _Float16*)lds;
        #pragma unroll
        for (int r = 0; r < 8; ++r) {
            const int off = (r * 256 + tid) * 8;
            *(half8*)(vdst + off) = *(const half8*)(vl + off);
        }
    }
}

// ================ K3: attention + output projection ========================
#define BH_OFF 0
#define BP_OFF 32768
#define LDS_B  40960

__global__ __launch_bounds__(256, 3)
void attn_out(const float* __restrict__ mask, const _Float16* __restrict__ ws,
              const float* __restrict__ bo, float* __restrict__ out) {
    extern __shared__ char lds[];
    const int tid = threadIdx.x;
    const int wid = tid >> 6;
    const int l15 = tid & 15;
    const int l4  = (tid & 63) >> 4;
    const int t   = blockIdx.x;
    const int b   = t >> 8, n = t & 255;

    const _Float16* qt = ws + QB + (size_t)t * 16384;   // [pos][ch]
    const _Float16* kt = ws + KB + (size_t)t * 16384;
    const _Float16* vt = ws + VB + (size_t)t * 16384;   // [ch][pos]
    const _Float16* WoF = ws + 3 * (size_t)WELEM;       // fragment-major

    // -------- S = (Q^T K)*scale + in-register masked softmax -> P ---------
    {
        const int i0 = wid * 16;
        f32x4 sa[4];
        #pragma unroll
        for (int jt = 0; jt < 4; ++jt) sa[jt] = (f32x4){0.f, 0.f, 0.f, 0.f};
        #pragma unroll
        for (int ks = 0; ks < 8; ++ks) {
            half8 qa = *(const half8*)(qt + (size_t)(i0 + l15) * CRED + ks * 32 + l4 * 8);
            #pragma unroll
            for (int jt = 0; jt < 4; ++jt) {
                half8 kf = *(const half8*)(kt + (size_t)(jt * 16 + l15) * CRED + ks * 32 + l4 * 8);
                sa[jt] = __builtin_amdgcn_mfma_f32_16x16x32_f16(qa, kf, sa[jt], 0, 0, 0);
            }
        }
        float msk[4];
        #pragma unroll
        for (int jt = 0; jt < 4; ++jt)
            msk[jt] = mask[(size_t)b * LL + n * 64 + jt * 16 + l15];
        #pragma unroll
        for (int ri = 0; ri < 4; ++ri) {
            float v[4];
            #pragma unroll
            for (int jt = 0; jt < 4; ++jt)
                v[jt] = (msk[jt] == 0.f) ? -1e30f : sa[jt][ri] * 0.0625f;
            float mx = fmaxf(fmaxf(v[0], v[1]), fmaxf(v[2], v[3]));
            mx = fmaxf(mx, __shfl_xor(mx, 1));
            mx = fmaxf(mx, __shfl_xor(mx, 2));
            mx = fmaxf(mx, __shfl_xor(mx, 4));
            mx = fmaxf(mx, __shfl_xor(mx, 8));
            float e[4], sum = 0.f;
            #pragma unroll
            for (int jt = 0; jt < 4; ++jt) { e[jt] = __expf(v[jt] - mx); sum += e[jt]; }
            sum += __shfl_xor(sum, 1);
            sum += __shfl_xor(sum, 2);
            sum += __shfl_xor(sum, 4);
            sum += __shfl_xor(sum, 8);
            const float inv = 1.f / sum;
            const int i = i0 + l4 * 4 + ri;
            #pragma unroll
            for (int jt = 0; jt < 4; ++jt) {
                const int j = jt * 16 + l15;
                *(_Float16*)(lds + BP_OFF + i * 128 + ((2 * j) ^ SWZ(i))) =
                    (_Float16)(e[jt] * inv);
            }
        }
    }
    __syncthreads();   // P ready

    // -------- H = relu(V @ P^T) -------------------------------------------
    {
        const int cb = wid * 64;
        f32x4 pv[4][4];
        #pragma unroll
        for (int m = 0; m < 4; ++m)
            #pragma unroll
            for (int q = 0; q < 4; ++q) pv[m][q] = (f32x4){0.f, 0.f, 0.f, 0.f};
        #pragma unroll
        for (int ks = 0; ks < 2; ++ks) {
            const int kb = ks * 64 + l4 * 16;
            half8 pb[4];
            #pragma unroll
            for (int nt = 0; nt < 4; ++nt) {
                const int i = nt * 16 + l15;
                pb[nt] = *(const half8*)(lds + BP_OFF + i * 128 + (kb ^ SWZ(i)));
            }
            #pragma unroll
            for (int mt = 0; mt < 4; ++mt) {
                half8 va = *(const half8*)(vt + (size_t)(cb + mt * 16 + l15) * 64 + ks * 32 + l4 * 8);
                #pragma unroll
                for (int nt = 0; nt < 4; ++nt)
                    pv[mt][nt] = __builtin_amdgcn_mfma_f32_16x16x32_f16(va, pb[nt], pv[mt][nt], 0, 0, 0);
            }
        }
        #pragma unroll
        for (int mt = 0; mt < 4; ++mt) {
            const int c0 = cb + mt * 16 + l4 * 4;
            #pragma unroll
            for (int nt = 0; nt < 4; ++nt) {
                const int j = nt * 16 + l15;
                union { _Float16 h[4]; uint64_t q; } hp;
                #pragma unroll
                for (int ri = 0; ri < 4; ++ri)
                    hp.h[ri] = (_Float16)fmaxf(pv[mt][nt][ri], 0.f);
                *(uint64_t*)(lds + BH_OFF + j * 512 + ((2 * c0) ^ SWZ(j))) = hp.q;
            }
        }
    }
    __syncthreads();   // H ready

    // -------- Out = Wo @ H + bo  (Wo fragment-major: contiguous frag loads)
    #pragma unroll
    for (int op = 0; op < 2; ++op) {
        const int mbo = wid * 128 + op * 64;
        f32x4 oa[4][4];
        #pragma unroll
        for (int m = 0; m < 4; ++m)
            #pragma unroll
            for (int q = 0; q < 4; ++q) oa[m][q] = (f32x4){0.f, 0.f, 0.f, 0.f};
        const _Float16* wof = WoF + (size_t)(wid * 8 + op * 4) * 4096 + l4 * 128 + l15 * 8;
        #pragma unroll 4
        for (int ks = 0; ks < 8; ++ks) {
            const int kb = ks * 64 + l4 * 16;
            half8 hb[4];
            #pragma unroll
            for (int nt = 0; nt < 4; ++nt) {
                const int i = nt * 16 + l15;
                hb[nt] = *(const half8*)(lds + BH_OFF + i * 512 + (kb ^ SWZ(i)));
            }
            #pragma unroll
            for (int mt = 0; mt < 4; ++mt) {
                half8 wa = *(const half8*)(wof + mt * 4096 + ks * 512);
                #pragma unroll
                for (int nt = 0; nt < 4; ++nt)
                    oa[mt][nt] = __builtin_amdgcn_mfma_f32_16x16x32_f16(wa, hb[nt], oa[mt][nt], 0, 0, 0);
            }
        }
        #pragma unroll
        for (int mt = 0; mt < 4; ++mt) {
            const int o0 = mbo + mt * 16 + l4 * 4;
            f32x4 bov = *(const f32x4*)(bo + o0);
            #pragma unroll
            for (int ri = 0; ri < 4; ++ri) {
                float* orow = out + ((size_t)b * CIN + (o0 + ri)) * LL + n * 64;
                #pragma unroll
                for (int nt = 0; nt < 4; ++nt)
                    orow[nt * 16 + l15] = oa[mt][nt][ri] + bov[ri];
            }
        }
    }
}

// ================= Fallback: R5 fused kernel (verified, 168 us) ============
#define XT_OFF 0
#define Q_OFF  0
#define K_OFF  32768
#define V_OFF  32768
#define H_OFF  0
#define P_OFF  65536
#define MSK_OFF 73728
#define LDS_BYTES 73984

__global__ __launch_bounds__(256, 2)
void att_fused(const float* __restrict__ x1, const float* __restrict__ mask,
               const _Float16* __restrict__ W,
               const float* __restrict__ bq, const float* __restrict__ bk,
               const float* __restrict__ bv, const float* __restrict__ bo,
               float* __restrict__ out) {
    extern __shared__ char lds[];
    const int tid  = threadIdx.x;
    const int wid  = tid >> 6;
    const int lane = tid & 63;
    const int l15  = lane & 15;
    const int l4   = lane >> 4;
    const int blk  = blockIdx.x;
    const int b    = blk >> 8;
    const int n    = blk & 255;

    const _Float16* Wq = W;
    const _Float16* Wk = W + WELEM;
    const _Float16* Wv = W + 2 * WELEM;
    const _Float16* Wo = W + 3 * WELEM;

    {
        const int jx = tid & 15;
        const int rb = tid >> 4;
        const float* xbase = x1 + ((size_t)b * CIN + 2 * rb) * LL + n * 64 + 4 * jx;
        #pragma unroll
        for (int i = 0; i < 16; ++i) {
            f32x4 a = *(const f32x4*)(xbase + (size_t)(32 * i) * LL);
            f32x4 c = *(const f32x4*)(xbase + (size_t)(32 * i + 1) * LL);
            const int col = 4 * rb + 64 * i;
            #pragma unroll
            for (int u = 0; u < 4; ++u) {
                union { _Float16 h[2]; uint32_t w; } p;
                p.h[0] = (_Float16)a[u];
                p.h[1] = (_Float16)c[u];
                const int j = 4 * jx + u;
                *(uint32_t*)(lds + XT_OFF + j * 1024 + (col ^ SWZ(j))) = p.w;
            }
        }
        if (tid < 64)
            *(float*)(lds + MSK_OFF + tid * 4) = mask[(size_t)b * LL + n * 64 + tid];
    }
    __syncthreads();

    uint64_t qh[4][4], kh[4][4], vh[4][4];
    #pragma unroll
    for (int pass = 0; pass < 4; ++pass) {
        f32x4 aQ[4], aK[4], aV[4];
        #pragma unroll
        for (int q = 0; q < 4; ++q) {
            aQ[q] = (f32x4){0.f, 0.f, 0.f, 0.f};
            aK[q] = (f32x4){0.f, 0.f, 0.f, 0.f};
            aV[q] = (f32x4){0.f, 0.f, 0.f, 0.f};
        }
        const int mrow = wid * 64 + pass * 16 + l15;
        const _Float16* wqp = Wq + (size_t)mrow * CIN + l4 * 8;
        const _Float16* wkp = Wk + (size_t)mrow * CIN + l4 * 8;
        const _Float16* wvp = Wv + (size_t)mrow * CIN + l4 * 8;
        #pragma unroll 4
        for (int ks = 0; ks < 16; ++ks) {
            const int kb = ks * 64 + l4 * 16;
            half8 xb[4];
            #pragma unroll
            for (int nt = 0; nt < 4; ++nt) {
                const int j = nt * 16 + l15;
                xb[nt] = *(const half8*)(lds + XT_OFF + j * 1024 + (kb ^ SWZ(j)));
            }
            half8 aq = *(const half8*)(wqp + ks * 32);
            half8 ak = *(const half8*)(wkp + ks * 32);
            half8 av = *(const half8*)(wvp + ks * 32);
            #pragma unroll
            for (int nt = 0; nt < 4; ++nt) {
                aQ[nt] = __builtin_amdgcn_mfma_f32_16x16x32_f16(aq, xb[nt], aQ[nt], 0, 0, 0);
                aK[nt] = __builtin_amdgcn_mfma_f32_16x16x32_f16(ak, xb[nt], aK[nt], 0, 0, 0);
                aV[nt] = __builtin_amdgcn_mfma_f32_16x16x32_f16(av, xb[nt], aV[nt], 0, 0, 0);
            }
        }
        const int c0 = wid * 64 + pass * 16 + l4 * 4;
        f32x4 bqv = *(const f32x4*)(bq + c0);
        f32x4 bkv = *(const f32x4*)(bk + c0);
        f32x4 bvv = *(const f32x4*)(bv + c0);
        #pragma unroll
        for (int nt = 0; nt < 4; ++nt) {
            union { _Float16 h[4]; uint64_t q; } qp, kp, vp;
            #pragma unroll
            for (int ri = 0; ri < 4; ++ri) {
                qp.h[ri] = (_Float16)(aQ[nt][ri] + bqv[ri]);
                kp.h[ri] = (_Float16)(aK[nt][ri] + bkv[ri]);
                vp.h[ri] = (_Float16)(aV[nt][ri] + bvv[ri]);
            }
            qh[pass][nt] = qp.q;
            kh[pass][nt] = kp.q;
            vh[pass][nt] = vp.q;
        }
    }
    __syncthreads();

    #pragma unroll
    for (int pass = 0; pass < 4; ++pass) {
        const int c0 = wid * 64 + pass * 16 + l4 * 4;
        #pragma unroll
        for (int nt = 0; nt < 4; ++nt) {
            const int j = nt * 16 + l15;
            *(uint64_t*)(lds + Q_OFF + j * 512 + ((2 * c0) ^ SWZ(j))) = qh[pass][nt];
            *(uint64_t*)(lds + K_OFF + j * 512 + ((2 * c0) ^ SWZ(j))) = kh[pass][nt];
        }
    }
    __syncthreads();

    {
        const int i0 = wid * 16;
        f32x4 sa[4];
        #pragma unroll
        for (int jt = 0; jt < 4; ++jt) sa[jt] = (f32x4){0.f, 0.f, 0.f, 0.f};
        #pragma unroll
        for (int ks = 0; ks < 8; ++ks) {
            const int kb = ks * 64 + l4 * 16;
            const int iq = i0 + l15;
            half8 qa = *(const half8*)(lds + Q_OFF + iq * 512 + (kb ^ SWZ(iq)));
            #pragma unroll
            for (int jt = 0; jt < 4; ++jt) {
                const int jr = jt * 16 + l15;
                half8 kf = *(const half8*)(lds + K_OFF + jr * 512 + (kb ^ SWZ(jr)));
                sa[jt] = __builtin_amdgcn_mfma_f32_16x16x32_f16(qa, kf, sa[jt], 0, 0, 0);
            }
        }
        float msk[4];
        #pragma unroll
        for (int jt = 0; jt < 4; ++jt)
            msk[jt] = *(const float*)(lds + MSK_OFF + (jt * 16 + l15) * 4);
        #pragma unroll
        for (int ri = 0; ri < 4; ++ri) {
            float v[4];
            #pragma unroll
            for (int jt = 0; jt < 4; ++jt)
                v[jt] = (msk[jt] == 0.f) ? -1e30f : sa[jt][ri] * 0.0625f;
            float mx = fmaxf(fmaxf(v[0], v[1]), fmaxf(v[2], v[3]));
            mx = fmaxf(mx, __shfl_xor(mx, 1));
            mx = fmaxf(mx, __shfl_xor(mx, 2));
            mx = fmaxf(mx, __shfl_xor(mx, 4));
            mx = fmaxf(mx, __shfl_xor(mx, 8));
            float e[4], sum = 0.f;
            #pragma unroll
            for (int jt = 0; jt < 4; ++jt) { e[jt] = __expf(v[jt] - mx); sum += e[jt]; }
            sum += __shfl_xor(sum, 1);
            sum += __shfl_xor(sum, 2);
            sum += __shfl_xor(sum, 4);
            sum += __shfl_xor(sum, 8);
            const float inv = 1.f / sum;
            const int i = i0 + l4 * 4 + ri;
            #pragma unroll
            for (int jt = 0; jt < 4; ++jt) {
                const int j = jt * 16 + l15;
                *(_Float16*)(lds + P_OFF + i * 128 + ((2 * j) ^ SWZ(i))) =
                    (_Float16)(e[jt] * inv);
            }
        }
    }
    __syncthreads();

    #pragma unroll
    for (int pass = 0; pass < 4; ++pass) {
        const int c0 = wid * 64 + pass * 16 + l4 * 4;
        #pragma unroll
        for (int nt = 0; nt < 4; ++nt) {
            const int j = nt * 16 + l15;
            const uint64_t v64 = vh[pass][nt];
            #pragma unroll
            for (int ri = 0; ri < 4; ++ri) {
                const int c = c0 + ri;
                *(uint16_t*)(lds + V_OFF + c * 128 + ((2 * j) ^ SWZ(c))) =
                    (uint16_t)(v64 >> (16 * ri));
            }
        }
    }
    __syncthreads();

    {
        const int cb = wid * 64;
        f32x4 pv[4][4];
        #pragma unroll
        for (int m = 0; m < 4; ++m)
            #pragma unroll
            for (int q = 0; q < 4; ++q) pv[m][q] = (f32x4){0.f, 0.f, 0.f, 0.f};
        #pragma unroll
        for (int ks = 0; ks < 2; ++ks) {
            const int kb = ks * 64 + l4 * 16;
            half8 pb[4];
            #pragma unroll
            for (int nt = 0; nt < 4; ++nt) {
                const int i = nt * 16 + l15;
                pb[nt] = *(const half8*)(lds + P_OFF + i * 128 + (kb ^ SWZ(i)));
            }
            #pragma unroll
            for (int mt = 0; mt < 4; ++mt) {
                const int c = cb + mt * 16 + l15;
                half8 va = *(const half8*)(lds + V_OFF + c * 128 + (kb ^ SWZ(c)));
                #pragma unroll
                for (int nt = 0; nt < 4; ++nt)
                    pv[mt][nt] = __builtin_amdgcn_mfma_f32_16x16x32_f16(va, pb[nt], pv[mt][nt], 0, 0, 0);
            }
        }
        #pragma unroll
        for (int mt = 0; mt < 4; ++mt) {
            const int c0 = cb + mt * 16 + l4 * 4;
            #pragma unroll
            for (int nt = 0; nt < 4; ++nt) {
                const int j = nt * 16 + l15;
                union { _Float16 h[4]; uint64_t q; } hp;
                #pragma unroll
                for (int ri = 0; ri < 4; ++ri)
                    hp.h[ri] = (_Float16)fmaxf(pv[mt][nt][ri], 0.f);
                *(uint64_t*)(lds + H_OFF + j * 512 + ((2 * c0) ^ SWZ(j))) = hp.q;
            }
        }
    }
    __syncthreads();

    #pragma unroll
    for (int op = 0; op < 2; ++op) {
        const int mbo = wid * 128 + op * 64;
        const _Float16* wob = Wo + (size_t)(mbo + l15) * CRED + l4 * 8;
        f32x4 oa[4][4];
        #pragma unroll
        for (int m = 0; m < 4; ++m)
            #pragma unroll
            for (int q = 0; q < 4; ++q) oa[m][q] = (f32x4){0.f, 0.f, 0.f, 0.f};
        #pragma unroll 4
        for (int ks = 0; ks < 8; ++ks) {
            const int kb = ks * 64 + l4 * 16;
            half8 hb[4];
            #pragma unroll
            for (int nt = 0; nt < 4; ++nt) {
                const int i = nt * 16 + l15;
                hb[nt] = *(const half8*)(lds + H_OFF + i * 512 + (kb ^ SWZ(i)));
            }
            #pragma unroll
            for (int mt = 0; mt < 4; ++mt) {
                half8 wa = *(const half8*)(wob + mt * 16 * CRED + ks * 32);
                #pragma unroll
                for (int nt = 0; nt < 4; ++nt)
                    oa[mt][nt] = __builtin_amdgcn_mfma_f32_16x16x32_f16(wa, hb[nt], oa[mt][nt], 0, 0, 0);
            }
        }
        #pragma unroll
        for (int mt = 0; mt < 4; ++mt) {
            const int o0 = mbo + mt * 16 + l4 * 4;
            f32x4 bov = *(const f32x4*)(bo + o0);
            #pragma unroll
            for (int ri = 0; ri < 4; ++ri) {
                float* orow = out + ((size_t)b * CIN + (o0 + ri)) * LL + n * 64;
                #pragma unroll
                for (int nt = 0; nt < 4; ++nt)
                    orow[nt * 16 + l15] = oa[mt][nt][ri] + bov[ri];
            }
        }
    }
}

extern "C" void kernel_launch(void* const* d_in, const int* in_sizes, int n_in,
                              void* d_out, int out_size, void* d_ws, size_t ws_size,
                              hipStream_t stream) {
    const float* x1   = (const float*)d_in[0];
    // d_in[1] = x2 : unused by the reference
    const float* mask = (const float*)d_in[2];
    const float* Wq   = (const float*)d_in[3];
    const float* bq   = (const float*)d_in[4];
    const float* Wk   = (const float*)d_in[5];
    const float* bk   = (const float*)d_in[6];
    const float* Wv   = (const float*)d_in[7];
    const float* bv   = (const float*)d_in[8];
    const float* Wo   = (const float*)d_in[9];
    const float* bo   = (const float*)d_in[10];
    float* out = (float*)d_out;
    _Float16* wbuf = (_Float16*)d_ws;

    if (ws_size >= WS_NEED) {
        convert_weights_fm<<<2048, 256, 0, stream>>>(Wq, Wk, Wv, Wo, wbuf);
        (void)hipFuncSetAttribute((const void*)qkv_fused,
                                  hipFuncAttributeMaxDynamicSharedMemorySize, 65536);
        qkv_fused<<<BB * NBLK, 256, 65536, stream>>>(x1, wbuf, bq, bk, bv, wbuf);
        attn_out<<<BB * NBLK, 256, LDS_B, stream>>>(mask, wbuf, bo, out);
    } else {
        convert_weights_rm<<<2048, 256, 0, stream>>>(Wq, Wk, Wv, Wo, wbuf);
        (void)hipFuncSetAttribute((const void*)att_fused,
                                  hipFuncAttributeMaxDynamicSharedMemorySize, LDS_BYTES);
        att_fused<<<BB * NBLK, 256, LDS_BYTES, stream>>>(x1, mask, wbuf, bq, bk, bv, bo, out);
    }
}

// Round 12
// 173.215 us; speedup vs baseline: 1.5078x; 1.0563x over previous
//
#include <hip/hip_runtime.h>
#include <hip/hip_fp16.h>
#include <stdint.h>

// Problem constants (B,C_IN,L fixed by the reference)
#define BB    4
#define CIN   512
#define CRED  256
#define LL    16384
#define NBLK  256      // L / 64
#define WELEM 131072   // elements per weight matrix

typedef _Float16 half8 __attribute__((ext_vector_type(8)));
typedef float    f32x4 __attribute__((ext_vector_type(4)));

#define SWZ(r) (((r)&7)<<4)

// ---------------- workspace layout (elements of _Float16) -----------------
// [0, 524288)  : weights, FRAGMENT-MAJOR
//   p<3 (K=512): addr = p*WELEM + m16*8192 + ks*512 + l4*128 + l15*8 + e
//   p=3 (K=256): addr = 3*WELEM + m16*4096 + ks*512 + l4*128 + l15*8 + e
// QB: Q [b][pos 16384][ch 256] ; KB same ; VB: V [b][ch 256][pos 16384]
#define QB      524288
#define KB      (QB + 16777216)
#define VB      (KB + 16777216)
#define WS_NEED ((size_t)(VB + 16777216) * 2)   // ~101.7 MB (proven available)

// ---- fragment-major weight conversion ----
__global__ void convert_weights_fm(const float* __restrict__ Wq,
                                   const float* __restrict__ Wk,
                                   const float* __restrict__ Wv,
                                   const float* __restrict__ Wo,
                                   _Float16* __restrict__ dst) {
    int i = blockIdx.x * blockDim.x + threadIdx.x;
    int p = i >> 17;
    int e17 = i & (WELEM - 1);
    const float* src = (p == 0) ? Wq : (p == 1) ? Wk : (p == 2) ? Wv : Wo;
    const int Kd = (p < 3) ? 512 : 256;
    const int sh = (p < 3) ? 13 : 12;
    const int m16 = e17 >> sh;
    const int rem = e17 & ((1 << sh) - 1);
    const int ks  = rem >> 9;
    const int l4  = (rem >> 7) & 3;
    const int l15 = (rem >> 3) & 15;
    const int ee  = rem & 7;
    const int r = m16 * 16 + l15;
    const int k = ks * 32 + l4 * 8 + ee;
    dst[(size_t)p * WELEM + e17] = (_Float16)src[(size_t)r * Kd + k];
}

// ---- row-major conversion (fallback path only) ----
__global__ void convert_weights_rm(const float* __restrict__ Wq,
                                   const float* __restrict__ Wk,
                                   const float* __restrict__ Wv,
                                   const float* __restrict__ Wo,
                                   _Float16* __restrict__ dst) {
    int i = blockIdx.x * blockDim.x + threadIdx.x;
    int m = i >> 17;
    int e = i & (WELEM - 1);
    const float* src = (m == 0) ? Wq : (m == 1) ? Wk : (m == 2) ? Wv : Wo;
    dst[(size_t)m * WELEM + e] = (_Float16)src[e];
}

// ================= K2: QKV v4 — 12 waves/CU, tiny LDS, 2-phase =============
// Grid 3072: p(3) x batch(4) x 64-pos tile(256). 256 thr / 4 waves,
// LB(256,3) -> 3 blocks/CU (attn_out's proven occupancy regime).
// LDS: ONLY the X tile, dbuf 2 x 8 KB, fragment-major [s][l4][pos64][8ch].
// Weights: direct from L2, fragment-major (512 B contiguous per instr).
// MFMA:global-load = 4:1 (attn_out's ratio).
__global__ __launch_bounds__(256, 3)
void qkv_v4(const float* __restrict__ x1, const _Float16* __restrict__ W,
            const float* __restrict__ bq, const float* __restrict__ bk,
            const float* __restrict__ bv, _Float16* __restrict__ ws) {
    __shared__ _Float16 bt[2][4096];       // 2 x 8 KB
    const int tid = threadIdx.x;
    const int wid = tid >> 6;
    const int l15 = tid & 15;
    const int l4  = (tid & 63) >> 4;
    const int p   = blockIdx.x >> 10;      // matrix 0..2
    const int t   = blockIdx.x & 1023;
    const int b   = t >> 8, n = t & 255;

    // staging map: thread = ch-quad c4 (16) x pos-quad pq (16)
    const int c4 = tid & 15;
    const int pq = tid >> 4;
    const float* xb = x1 + ((size_t)b * CIN + 4 * c4) * LL + n * 64 + 4 * pq;
    const int sH  = c4 >> 3;               // ks-half within BK=64
    const int l4b = (c4 >> 1) & 3;
    const int e0  = (c4 & 1) * 4;

    f32x4 st[4];
    #define X_ISSUE(KT) do {                                                  \
        _Pragma("unroll")                                                     \
        for (int i_ = 0; i_ < 4; ++i_)                                        \
            st[i_] = *(const f32x4*)(xb + (size_t)((KT) * 64 + i_) * LL);     \
    } while (0)
    // fragment-major commit: el = s*2048 + l4*512 + pos*8 + e
    #define X_COMMIT(BUF) do {                                                \
        _Pragma("unroll")                                                     \
        for (int u_ = 0; u_ < 4; ++u_) {                                      \
            union { _Float16 h[4]; uint64_t q; } pk_;                         \
            _Pragma("unroll")                                                 \
            for (int i_ = 0; i_ < 4; ++i_) pk_.h[i_] = (_Float16)st[i_][u_];  \
            *(uint64_t*)(&bt[BUF][sH * 2048 + l4b * 512 + (4 * pq + u_) * 8 + e0]) = pk_.q; \
        }                                                                     \
    } while (0)

    X_ISSUE(0);
    X_COMMIT(0);
    __syncthreads();

    f32x4 acc[4][4];
    #pragma unroll
    for (int mt = 0; mt < 4; ++mt)
        #pragma unroll
        for (int q = 0; q < 4; ++q) acc[mt][q] = (f32x4){0.f, 0.f, 0.f, 0.f};

    const _Float16* wf0 = W + (size_t)p * WELEM + (size_t)(wid * 4) * 8192
                        + l4 * 128 + l15 * 8;

    #pragma unroll
    for (int kt = 0; kt < 8; ++kt) {
        const int cur = kt & 1;
        if (kt < 7) X_ISSUE(kt + 1);       // T14: issue before compute
        #pragma unroll
        for (int s = 0; s < 2; ++s) {
            const int ks = kt * 2 + s;
            half8 xf[4], wf[4];
            #pragma unroll
            for (int nt = 0; nt < 4; ++nt)
                xf[nt] = *(const half8*)(&bt[cur][s * 2048 + l4 * 512 + (nt * 16 + l15) * 8]);
            #pragma unroll
            for (int mt = 0; mt < 4; ++mt)
                wf[mt] = *(const half8*)(wf0 + mt * 8192 + ks * 512);
            #pragma unroll
            for (int mt = 0; mt < 4; ++mt)
                #pragma unroll
                for (int nt = 0; nt < 4; ++nt)
                    acc[mt][nt] = __builtin_amdgcn_mfma_f32_16x16x32_f16(
                        wf[mt], xf[nt], acc[mt][nt], 0, 0, 0);
        }
        if (kt < 7) X_COMMIT(cur ^ 1);     // commit late (loads landed)
        __syncthreads();
    }
    #undef X_ISSUE
    #undef X_COMMIT

    // -------- epilogue: +bias, store to Q/K ([pos][ch]) or V ([ch][pos]) ---
    const float* bias = (p == 0) ? bq : (p == 1) ? bk : bv;
    if (p < 2) {
        _Float16* dst = ws + (p ? KB : QB) + ((size_t)b * LL + n * 64) * CRED;
        #pragma unroll
        for (int mt = 0; mt < 4; ++mt) {
            const int c0 = wid * 64 + mt * 16 + l4 * 4;
            f32x4 b4 = *(const f32x4*)(bias + c0);
            #pragma unroll
            for (int nt = 0; nt < 4; ++nt) {
                const int pos = nt * 16 + l15;
                union { _Float16 h[4]; uint64_t q; } pk;
                #pragma unroll
                for (int ri = 0; ri < 4; ++ri)
                    pk.h[ri] = (_Float16)(acc[mt][nt][ri] + b4[ri]);
                *(uint64_t*)(dst + (size_t)pos * CRED + c0) = pk.q;
            }
        }
    } else {
        _Float16* vd = ws + VB + (size_t)b * CRED * LL + n * 64;
        #pragma unroll
        for (int mt = 0; mt < 4; ++mt) {
            const int c0 = wid * 64 + mt * 16 + l4 * 4;
            f32x4 b4 = *(const f32x4*)(bias + c0);
            #pragma unroll
            for (int nt = 0; nt < 4; ++nt) {
                const int pos = nt * 16 + l15;
                #pragma unroll
                for (int ri = 0; ri < 4; ++ri)
                    vd[(size_t)(c0 + ri) * LL + pos] =
                        (_Float16)(acc[mt][nt][ri] + b4[ri]);
            }
        }
    }
}

// ================ K3: attention + output projection (proven ~35 us) ========
#define BH_OFF 0
#define BP_OFF 32768
#define LDS_B  40960

__global__ __launch_bounds__(256, 3)
void attn_out(const float* __restrict__ mask, const _Float16* __restrict__ ws,
              const float* __restrict__ bo, float* __restrict__ out) {
    extern __shared__ char lds[];
    const int tid = threadIdx.x;
    const int wid = tid >> 6;
    const int l15 = tid & 15;
    const int l4  = (tid & 63) >> 4;
    const int b   = blockIdx.x >> 8;
    const int n   = blockIdx.x & 255;

    const _Float16* qt = ws + QB + ((size_t)b * LL + n * 64) * CRED;
    const _Float16* kt = ws + KB + ((size_t)b * LL + n * 64) * CRED;
    const _Float16* vt = ws + VB + (size_t)b * CRED * LL + n * 64;
    const _Float16* WoF = ws + 3 * (size_t)WELEM;       // fragment-major

    // -------- S = (Q^T K)*scale + in-register masked softmax -> P ---------
    {
        const int i0 = wid * 16;
        f32x4 sa[4];
        #pragma unroll
        for (int jt = 0; jt < 4; ++jt) sa[jt] = (f32x4){0.f, 0.f, 0.f, 0.f};
        #pragma unroll
        for (int ks = 0; ks < 8; ++ks) {
            half8 qa = *(const half8*)(qt + (size_t)(i0 + l15) * CRED + ks * 32 + l4 * 8);
            #pragma unroll
            for (int jt = 0; jt < 4; ++jt) {
                half8 kf = *(const half8*)(kt + (size_t)(jt * 16 + l15) * CRED + ks * 32 + l4 * 8);
                sa[jt] = __builtin_amdgcn_mfma_f32_16x16x32_f16(qa, kf, sa[jt], 0, 0, 0);
            }
        }
        float msk[4];
        #pragma unroll
        for (int jt = 0; jt < 4; ++jt)
            msk[jt] = mask[(size_t)b * LL + n * 64 + jt * 16 + l15];
        #pragma unroll
        for (int ri = 0; ri < 4; ++ri) {
            float v[4];
            #pragma unroll
            for (int jt = 0; jt < 4; ++jt)
                v[jt] = (msk[jt] == 0.f) ? -1e30f : sa[jt][ri] * 0.0625f;
            float mx = fmaxf(fmaxf(v[0], v[1]), fmaxf(v[2], v[3]));
            mx = fmaxf(mx, __shfl_xor(mx, 1));
            mx = fmaxf(mx, __shfl_xor(mx, 2));
            mx = fmaxf(mx, __shfl_xor(mx, 4));
            mx = fmaxf(mx, __shfl_xor(mx, 8));
            float e[4], sum = 0.f;
            #pragma unroll
            for (int jt = 0; jt < 4; ++jt) { e[jt] = __expf(v[jt] - mx); sum += e[jt]; }
            sum += __shfl_xor(sum, 1);
            sum += __shfl_xor(sum, 2);
            sum += __shfl_xor(sum, 4);
            sum += __shfl_xor(sum, 8);
            const float inv = 1.f / sum;
            const int i = i0 + l4 * 4 + ri;
            #pragma unroll
            for (int jt = 0; jt < 4; ++jt) {
                const int j = jt * 16 + l15;
                *(_Float16*)(lds + BP_OFF + i * 128 + ((2 * j) ^ SWZ(i))) =
                    (_Float16)(e[jt] * inv);
            }
        }
    }
    __syncthreads();   // P ready

    // -------- H = relu(V @ P^T) -------------------------------------------
    {
        const int cb = wid * 64;
        f32x4 pv[4][4];
        #pragma unroll
        for (int m = 0; m < 4; ++m)
            #pragma unroll
            for (int q = 0; q < 4; ++q) pv[m][q] = (f32x4){0.f, 0.f, 0.f, 0.f};
        #pragma unroll
        for (int ks = 0; ks < 2; ++ks) {
            const int kb = ks * 64 + l4 * 16;
            half8 pb[4];
            #pragma unroll
            for (int nt = 0; nt < 4; ++nt) {
                const int i = nt * 16 + l15;
                pb[nt] = *(const half8*)(lds + BP_OFF + i * 128 + (kb ^ SWZ(i)));
            }
            #pragma unroll
            for (int mt = 0; mt < 4; ++mt) {
                half8 va = *(const half8*)(vt + (size_t)(cb + mt * 16 + l15) * LL + ks * 32 + l4 * 8);
                #pragma unroll
                for (int nt = 0; nt < 4; ++nt)
                    pv[mt][nt] = __builtin_amdgcn_mfma_f32_16x16x32_f16(va, pb[nt], pv[mt][nt], 0, 0, 0);
            }
        }
        #pragma unroll
        for (int mt = 0; mt < 4; ++mt) {
            const int c0 = cb + mt * 16 + l4 * 4;
            #pragma unroll
            for (int nt = 0; nt < 4; ++nt) {
                const int j = nt * 16 + l15;
                union { _Float16 h[4]; uint64_t q; } hp;
                #pragma unroll
                for (int ri = 0; ri < 4; ++ri)
                    hp.h[ri] = (_Float16)fmaxf(pv[mt][nt][ri], 0.f);
                *(uint64_t*)(lds + BH_OFF + j * 512 + ((2 * c0) ^ SWZ(j))) = hp.q;
            }
        }
    }
    __syncthreads();   // H ready

    // -------- Out = Wo @ H + bo  (Wo fragment-major) ----------------------
    #pragma unroll
    for (int op = 0; op < 2; ++op) {
        const int mbo = wid * 128 + op * 64;
        f32x4 oa[4][4];
        #pragma unroll
        for (int m = 0; m < 4; ++m)
            #pragma unroll
            for (int q = 0; q < 4; ++q) oa[m][q] = (f32x4){0.f, 0.f, 0.f, 0.f};
        const _Float16* wof = WoF + (size_t)(wid * 8 + op * 4) * 4096 + l4 * 128 + l15 * 8;
        #pragma unroll 4
        for (int ks = 0; ks < 8; ++ks) {
            const int kb = ks * 64 + l4 * 16;
            half8 hb[4];
            #pragma unroll
            for (int nt = 0; nt < 4; ++nt) {
                const int i = nt * 16 + l15;
                hb[nt] = *(const half8*)(lds + BH_OFF + i * 512 + (kb ^ SWZ(i)));
            }
            #pragma unroll
            for (int mt = 0; mt < 4; ++mt) {
                half8 wa = *(const half8*)(wof + mt * 4096 + ks * 512);
                #pragma unroll
                for (int nt = 0; nt < 4; ++nt)
                    oa[mt][nt] = __builtin_amdgcn_mfma_f32_16x16x32_f16(wa, hb[nt], oa[mt][nt], 0, 0, 0);
            }
        }
        #pragma unroll
        for (int mt = 0; mt < 4; ++mt) {
            const int o0 = mbo + mt * 16 + l4 * 4;
            f32x4 bov = *(const f32x4*)(bo + o0);
            #pragma unroll
            for (int ri = 0; ri < 4; ++ri) {
                float* orow = out + ((size_t)b * CIN + (o0 + ri)) * LL + n * 64;
                #pragma unroll
                for (int nt = 0; nt < 4; ++nt)
                    orow[nt * 16 + l15] = oa[mt][nt][ri] + bov[ri];
            }
        }
    }
}

// ================= Fallback: R5 fused kernel (verified, 168 us) ============
#define XT_OFF 0
#define Q_OFF  0
#define K_OFF  32768
#define V_OFF  32768
#define H_OFF  0
#define P_OFF  65536
#define MSK_OFF 73728
#define LDS_BYTES 73984

__global__ __launch_bounds__(256, 2)
void att_fused(const float* __restrict__ x1, const float* __restrict__ mask,
               const _Float16* __restrict__ W,
               const float* __restrict__ bq, const float* __restrict__ bk,
               const float* __restrict__ bv, const float* __restrict__ bo,
               float* __restrict__ out) {
    extern __shared__ char lds[];
    const int tid  = threadIdx.x;
    const int wid  = tid >> 6;
    const int lane = tid & 63;
    const int l15  = lane & 15;
    const int l4   = lane >> 4;
    const int blk  = blockIdx.x;
    const int b    = blk >> 8;
    const int n    = blk & 255;

    const _Float16* Wq = W;
    const _Float16* Wk = W + WELEM;
    const _Float16* Wv = W + 2 * WELEM;
    const _Float16* Wo = W + 3 * WELEM;

    {
        const int jx = tid & 15;
        const int rb = tid >> 4;
        const float* xbase = x1 + ((size_t)b * CIN + 2 * rb) * LL + n * 64 + 4 * jx;
        #pragma unroll
        for (int i = 0; i < 16; ++i) {
            f32x4 a = *(const f32x4*)(xbase + (size_t)(32 * i) * LL);
            f32x4 c = *(const f32x4*)(xbase + (size_t)(32 * i + 1) * LL);
            const int col = 4 * rb + 64 * i;
            #pragma unroll
            for (int u = 0; u < 4; ++u) {
                union { _Float16 h[2]; uint32_t w; } p;
                p.h[0] = (_Float16)a[u];
                p.h[1] = (_Float16)c[u];
                const int j = 4 * jx + u;
                *(uint32_t*)(lds + XT_OFF + j * 1024 + (col ^ SWZ(j))) = p.w;
            }
        }
        if (tid < 64)
            *(float*)(lds + MSK_OFF + tid * 4) = mask[(size_t)b * LL + n * 64 + tid];
    }
    __syncthreads();

    uint64_t qh[4][4], kh[4][4], vh[4][4];
    #pragma unroll
    for (int pass = 0; pass < 4; ++pass) {
        f32x4 aQ[4], aK[4], aV[4];
        #pragma unroll
        for (int q = 0; q < 4; ++q) {
            aQ[q] = (f32x4){0.f, 0.f, 0.f, 0.f};
            aK[q] = (f32x4){0.f, 0.f, 0.f, 0.f};
            aV[q] = (f32x4){0.f, 0.f, 0.f, 0.f};
        }
        const int mrow = wid * 64 + pass * 16 + l15;
        const _Float16* wqp = Wq + (size_t)mrow * CIN + l4 * 8;
        const _Float16* wkp = Wk + (size_t)mrow * CIN + l4 * 8;
        const _Float16* wvp = Wv + (size_t)mrow * CIN + l4 * 8;
        #pragma unroll 4
        for (int ks = 0; ks < 16; ++ks) {
            const int kb = ks * 64 + l4 * 16;
            half8 xb[4];
            #pragma unroll
            for (int nt = 0; nt < 4; ++nt) {
                const int j = nt * 16 + l15;
                xb[nt] = *(const half8*)(lds + XT_OFF + j * 1024 + (kb ^ SWZ(j)));
            }
            half8 aq = *(const half8*)(wqp + ks * 32);
            half8 ak = *(const half8*)(wkp + ks * 32);
            half8 av = *(const half8*)(wvp + ks * 32);
            #pragma unroll
            for (int nt = 0; nt < 4; ++nt) {
                aQ[nt] = __builtin_amdgcn_mfma_f32_16x16x32_f16(aq, xb[nt], aQ[nt], 0, 0, 0);
                aK[nt] = __builtin_amdgcn_mfma_f32_16x16x32_f16(ak, xb[nt], aK[nt], 0, 0, 0);
                aV[nt] = __builtin_amdgcn_mfma_f32_16x16x32_f16(av, xb[nt], aV[nt], 0, 0, 0);
            }
        }
        const int c0 = wid * 64 + pass * 16 + l4 * 4;
        f32x4 bqv = *(const f32x4*)(bq + c0);
        f32x4 bkv = *(const f32x4*)(bk + c0);
        f32x4 bvv = *(const f32x4*)(bv + c0);
        #pragma unroll
        for (int nt = 0; nt < 4; ++nt) {
            union { _Float16 h[4]; uint64_t q; } qp, kp, vp;
            #pragma unroll
            for (int ri = 0; ri < 4; ++ri) {
                qp.h[ri] = (_Float16)(aQ[nt][ri] + bqv[ri]);
                kp.h[ri] = (_Float16)(aK[nt][ri] + bkv[ri]);
                vp.h[ri] = (_Float16)(aV[nt][ri] + bvv[ri]);
            }
            qh[pass][nt] = qp.q;
            kh[pass][nt] = kp.q;
            vh[pass][nt] = vp.q;
        }
    }
    __syncthreads();

    #pragma unroll
    for (int pass = 0; pass < 4; ++pass) {
        const int c0 = wid * 64 + pass * 16 + l4 * 4;
        #pragma unroll
        for (int nt = 0; nt < 4; ++nt) {
            const int j = nt * 16 + l15;
            *(uint64_t*)(lds + Q_OFF + j * 512 + ((2 * c0) ^ SWZ(j))) = qh[pass][nt];
            *(uint64_t*)(lds + K_OFF + j * 512 + ((2 * c0) ^ SWZ(j))) = kh[pass][nt];
        }
    }
    __syncthreads();

    {
        const int i0 = wid * 16;
        f32x4 sa[4];
        #pragma unroll
        for (int jt = 0; jt < 4; ++jt) sa[jt] = (f32x4){0.f, 0.f, 0.f, 0.f};
        #pragma unroll
        for (int ks = 0; ks < 8; ++ks) {
            const int kb = ks * 64 + l4 * 16;
            const int iq = i0 + l15;
            half8 qa = *(const half8*)(lds + Q_OFF + iq * 512 + (kb ^ SWZ(iq)));
            #pragma unroll
            for (int jt = 0; jt < 4; ++jt) {
                const int jr = jt * 16 + l15;
                half8 kf = *(const half8*)(lds + K_OFF + jr * 512 + (kb ^ SWZ(jr)));
                sa[jt] = __builtin_amdgcn_mfma_f32_16x16x32_f16(qa, kf, sa[jt], 0, 0, 0);
            }
        }
        float msk[4];
        #pragma unroll
        for (int jt = 0; jt < 4; ++jt)
            msk[jt] = *(const float*)(lds + MSK_OFF + (jt * 16 + l15) * 4);
        #pragma unroll
        for (int ri = 0; ri < 4; ++ri) {
            float v[4];
            #pragma unroll
            for (int jt = 0; jt < 4; ++jt)
                v[jt] = (msk[jt] == 0.f) ? -1e30f : sa[jt][ri] * 0.0625f;
            float mx = fmaxf(fmaxf(v[0], v[1]), fmaxf(v[2], v[3]));
            mx = fmaxf(mx, __shfl_xor(mx, 1));
            mx = fmaxf(mx, __shfl_xor(mx, 2));
            mx = fmaxf(mx, __shfl_xor(mx, 4));
            mx = fmaxf(mx, __shfl_xor(mx, 8));
            float e[4], sum = 0.f;
            #pragma unroll
            for (int jt = 0; jt < 4; ++jt) { e[jt] = __expf(v[jt] - mx); sum += e[jt]; }
            sum += __shfl_xor(sum, 1);
            sum += __shfl_xor(sum, 2);
            sum += __shfl_xor(sum, 4);
            sum += __shfl_xor(sum, 8);
            const float inv = 1.f / sum;
            const int i = i0 + l4 * 4 + ri;
            #pragma unroll
            for (int jt = 0; jt < 4; ++jt) {
                const int j = jt * 16 + l15;
                *(_Float16*)(lds + P_OFF + i * 128 + ((2 * j) ^ SWZ(i))) =
                    (_Float16)(e[jt] * inv);
            }
        }
    }
    __syncthreads();

    #pragma unroll
    for (int pass = 0; pass < 4; ++pass) {
        const int c0 = wid * 64 + pass * 16 + l4 * 4;
        #pragma unroll
        for (int nt = 0; nt < 4; ++nt) {
            const int j = nt * 16 + l15;
            const uint64_t v64 = vh[pass][nt];
            #pragma unroll
            for (int ri = 0; ri < 4; ++ri) {
                const int c = c0 + ri;
                *(uint16_t*)(lds + V_OFF + c * 128 + ((2 * j) ^ SWZ(c))) =
                    (uint16_t)(v64 >> (16 * ri));
            }
        }
    }
    __syncthreads();

    {
        const int cb = wid * 64;
        f32x4 pv[4][4];
        #pragma unroll
        for (int m = 0; m < 4; ++m)
            #pragma unroll
            for (int q = 0; q < 4; ++q) pv[m][q] = (f32x4){0.f, 0.f, 0.f, 0.f};
        #pragma unroll
        for (int ks = 0; ks < 2; ++ks) {
            const int kb = ks * 64 + l4 * 16;
            half8 pb[4];
            #pragma unroll
            for (int nt = 0; nt < 4; ++nt) {
                const int i = nt * 16 + l15;
                pb[nt] = *(const half8*)(lds + P_OFF + i * 128 + (kb ^ SWZ(i)));
            }
            #pragma unroll
            for (int mt = 0; mt < 4; ++mt) {
                const int c = cb + mt * 16 + l15;
                half8 va = *(const half8*)(lds + V_OFF + c * 128 + (kb ^ SWZ(c)));
                #pragma unroll
                for (int nt = 0; nt < 4; ++nt)
                    pv[mt][nt] = __builtin_amdgcn_mfma_f32_16x16x32_f16(va, pb[nt], pv[mt][nt], 0, 0, 0);
            }
        }
        #pragma unroll
        for (int mt = 0; mt < 4; ++mt) {
            const int c0 = cb + mt * 16 + l4 * 4;
            #pragma unroll
            for (int nt = 0; nt < 4; ++nt) {
                const int j = nt * 16 + l15;
                union { _Float16 h[4]; uint64_t q; } hp;
                #pragma unroll
                for (int ri = 0; ri < 4; ++ri)
                    hp.h[ri] = (_Float16)fmaxf(pv[mt][nt][ri], 0.f);
                *(uint64_t*)(lds + H_OFF + j * 512 + ((2 * c0) ^ SWZ(j))) = hp.q;
            }
        }
    }
    __syncthreads();

    #pragma unroll
    for (int op = 0; op < 2; ++op) {
        const int mbo = wid * 128 + op * 64;
        const _Float16* wob = Wo + (size_t)(mbo + l15) * CRED + l4 * 8;
        f32x4 oa[4][4];
        #pragma unroll
        for (int m = 0; m < 4; ++m)
            #pragma unroll
            for (int q = 0; q < 4; ++q) oa[m][q] = (f32x4){0.f, 0.f, 0.f, 0.f};
        #pragma unroll 4
        for (int ks = 0; ks < 8; ++ks) {
            const int kb = ks * 64 + l4 * 16;
            half8 hb[4];
            #pragma unroll
            for (int nt = 0; nt < 4; ++nt) {
                const int i = nt * 16 + l15;
                hb[nt] = *(const half8*)(lds + H_OFF + i * 512 + (kb ^ SWZ(i)));
            }
            #pragma unroll
            for (int mt = 0; mt < 4; ++mt) {
                half8 wa = *(const half8*)(wob + mt * 16 * CRED + ks * 32);
                #pragma unroll
                for (int nt = 0; nt < 4; ++nt)
                    oa[mt][nt] = __builtin_amdgcn_mfma_f32_16x16x32_f16(wa, hb[nt], oa[mt][nt], 0, 0, 0);
            }
        }
        #pragma unroll
        for (int mt = 0; mt < 4; ++mt) {
            const int o0 = mbo + mt * 16 + l4 * 4;
            f32x4 bov = *(const f32x4*)(bo + o0);
            #pragma unroll
            for (int ri = 0; ri < 4; ++ri) {
                float* orow = out + ((size_t)b * CIN + (o0 + ri)) * LL + n * 64;
                #pragma unroll
                for (int nt = 0; nt < 4; ++nt)
                    orow[nt * 16 + l15] = oa[mt][nt][ri] + bov[ri];
            }
        }
    }
}

extern "C" void kernel_launch(void* const* d_in, const int* in_sizes, int n_in,
                              void* d_out, int out_size, void* d_ws, size_t ws_size,
                              hipStream_t stream) {
    const float* x1   = (const float*)d_in[0];
    // d_in[1] = x2 : unused by the reference
    const float* mask = (const float*)d_in[2];
    const float* Wq   = (const float*)d_in[3];
    const float* bq   = (const float*)d_in[4];
    const float* Wk   = (const float*)d_in[5];
    const float* bk   = (const float*)d_in[6];
    const float* Wv   = (const float*)d_in[7];
    const float* bv   = (const float*)d_in[8];
    const float* Wo   = (const float*)d_in[9];
    const float* bo   = (const float*)d_in[10];
    float* out = (float*)d_out;
    _Float16* wbuf = (_Float16*)d_ws;

    if (ws_size >= WS_NEED) {
        convert_weights_fm<<<2048, 256, 0, stream>>>(Wq, Wk, Wv, Wo, wbuf);
        qkv_v4<<<3 * BB * NBLK, 256, 0, stream>>>(x1, wbuf, bq, bk, bv, wbuf);
        attn_out<<<BB * NBLK, 256, LDS_B, stream>>>(mask, wbuf, bo, out);
    } else {
        convert_weights_rm<<<2048, 256, 0, stream>>>(Wq, Wk, Wv, Wo, wbuf);
        (void)hipFuncSetAttribute((const void*)att_fused,
                                  hipFuncAttributeMaxDynamicSharedMemorySize, LDS_BYTES);
        att_fused<<<BB * NBLK, 256, LDS_BYTES, stream>>>(x1, mask, wbuf, bq, bk, bv, bo, out);
    }
}